// Round 6
// baseline (169.467 us; speedup 1.0000x reference)
//
#include <hip/hip_runtime.h>

#define DEV __device__ __forceinline__

constexpr int D  = 2048;
constexpr int H  = 16;
constexpr int DH = 128;
constexpr int S  = 8192;
constexpr float EPS = 1e-6f;
constexpr float SCALE = 0.08838834764831845f; // DH^-0.5
constexpr int RSTRIDE = 2056; // LDS row stride in bf16 (2048 + 8 pad: stride 4112B -> 2-way bank alias only)

typedef unsigned short ushortv4 __attribute__((ext_vector_type(4)));
typedef short bf16x8 __attribute__((ext_vector_type(8)));
typedef float f32x4 __attribute__((ext_vector_type(4)));

DEV float bf2f(unsigned short u){ return __uint_as_float(((unsigned int)u) << 16); }
DEV unsigned short f2bf(float f){
  unsigned int x = __float_as_uint(f);
  unsigned int r = x + 0x7fffu + ((x >> 16) & 1u);
  return (unsigned short)(r >> 16);
}

DEV float gelu(float x){
  float x3 = x * x * x;
  return 0.5f * x * (1.f + tanhf(0.7978845608028654f * (x + 0.044715f * x3)));
}

// block-wide sum of two values; block = NW*64 threads
template<int NW>
DEV void block_sum2(float& a, float& b, float* buf){
  #pragma unroll
  for(int o = 32; o; o >>= 1){ a += __shfl_xor(a, o); b += __shfl_xor(b, o); }
  const int w = threadIdx.x >> 6;
  if((threadIdx.x & 63) == 0){ buf[w] = a; buf[NW + w] = b; }
  __syncthreads();
  a = buf[0]; b = buf[NW];
  #pragma unroll
  for(int i = 1; i < NW; i++){ a += buf[i]; b += buf[NW + i]; }
}

// ---------------- K1: q = LN(self_tok) @ wq + bq (64 blocks x 512) ----------------
__global__ __launch_bounds__(512) void k_q(const float* __restrict__ st,
    const float* __restrict__ g1, const float* __restrict__ b1,
    const float* __restrict__ wq, const float* __restrict__ bq,
    float* __restrict__ q){
  __shared__ float buf[16];
  __shared__ float ns[D];
  __shared__ float red[16][32];
  const int t = threadIdx.x;
  float4 a = ((const float4*)st)[t];
  float sum = a.x + a.y + a.z + a.w;
  float sq  = a.x*a.x + a.y*a.y + a.z*a.z + a.w*a.w;
  block_sum2<8>(sum, sq, buf);
  const float m = sum * (1.f / D);
  const float r = rsqrtf(sq * (1.f / D) - m * m + EPS);
  float4 g = ((const float4*)g1)[t], b = ((const float4*)b1)[t];
  float4 na;
  na.x = (a.x - m) * r * g.x + b.x;
  na.y = (a.y - m) * r * g.y + b.y;
  na.z = (a.z - m) * r * g.z + b.z;
  na.w = (a.w - m) * r * g.w + b.w;
  ((float4*)ns)[t] = na;
  __syncthreads();
  const int i = blockIdx.x * 32 + (t & 31);
  const int sl = t >> 5;   // 0..15
  float acc = 0.f;
  #pragma unroll 8
  for(int jj = 0; jj < 128; jj++){
    int j = sl * 128 + jj;
    acc = fmaf(ns[j], wq[(size_t)j * D + i], acc);
  }
  red[sl][t & 31] = acc;
  __syncthreads();
  if(t < 32){
    float s = bq[blockIdx.x * 32 + t];
    #pragma unroll
    for(int p = 0; p < 16; p++) s += red[p][t];
    q[blockIdx.x * 32 + t] = s;
  }
}

// ---------------- K2: wkqT[h][j] (bf16) = wk[j, h*128:+128].q ; qb[h] = bk.q ----------------
__global__ __launch_bounds__(256) void k_wkq(const float* __restrict__ wk,
    const float* __restrict__ bk, const float* __restrict__ q,
    unsigned short* __restrict__ wkqT, float* __restrict__ qb){
  const int j = blockIdx.x, t = threadIdx.x;
  const float* src = (j < D) ? (wk + (size_t)j * D) : bk;
  const float4* s4 = (const float4*)src;
  const float4* q4 = (const float4*)q;
  float4 a = s4[2 * t], c = s4[2 * t + 1], qa = q4[2 * t], qc = q4[2 * t + 1];
  float p = a.x*qa.x + a.y*qa.y + a.z*qa.z + a.w*qa.w
          + c.x*qc.x + c.y*qc.y + c.z*qc.z + c.w*qc.w;
  #pragma unroll
  for(int o = 1; o < 16; o <<= 1) p += __shfl_xor(p, o);
  if((t & 15) == 0){
    const int h = t >> 4;
    if(j < D) wkqT[(size_t)h * D + j] = f2bf(p);
    else      qb[h] = p;
  }
}

// ---------------- K3: LN(all_toks)->n_all bf16 fused with MFMA scores ----------------
// 512 threads, 16 rows/block. LN: wave w does rows 2w,2w+1 (reg-held, no spill).
// MFMA: wave w covers K=256 chunk (8 mfma), B-frags from LDS rows, A from L2 wkqT.
__global__ __launch_bounds__(512, 4) void k_ln_sc(
    const float* __restrict__ at, const float* __restrict__ g1,
    const float* __restrict__ b1, const unsigned short* __restrict__ wkqT,
    const float* __restrict__ qb, unsigned short* __restrict__ nall,
    float* __restrict__ scores, float* __restrict__ bm, float* __restrict__ bs){
  __shared__ unsigned short rows[16 * RSTRIDE]; // 65792 B
  __shared__ f32x4 cred[8][64];                 // 8192 B
  const int t = threadIdx.x;
  const int w = t >> 6, l = t & 63;
  const int s0 = blockIdx.x * 16;
  #pragma unroll
  for(int rp = 0; rp < 2; rp++){
    const int r = 2 * w + rp;
    const size_t s = s0 + r;
    const float4* row4 = (const float4*)(at + s * D);
    float4 a[8];
    float sum = 0.f, sq = 0.f;
    #pragma unroll
    for(int k = 0; k < 8; k++){
      a[k] = row4[l + 64 * k];
      sum += a[k].x + a[k].y + a[k].z + a[k].w;
      sq  += a[k].x*a[k].x + a[k].y*a[k].y + a[k].z*a[k].z + a[k].w*a[k].w;
    }
    #pragma unroll
    for(int o = 32; o; o >>= 1){ sum += __shfl_xor(sum, o); sq += __shfl_xor(sq, o); }
    const float m = sum * (1.f / D);
    const float rs = rsqrtf(sq * (1.f / D) - m * m + EPS);
    const float4* g4 = (const float4*)g1;
    const float4* b4 = (const float4*)b1;
    ushortv4* nst = (ushortv4*)(nall + s * D);
    ushortv4* lst = (ushortv4*)(rows + r * RSTRIDE);
    #pragma unroll
    for(int k = 0; k < 8; k++){
      const int j4 = l + 64 * k;
      float4 gg = g4[j4], bb = b4[j4];
      ushortv4 o4;
      o4[0] = f2bf((a[k].x - m) * rs * gg.x + bb.x);
      o4[1] = f2bf((a[k].y - m) * rs * gg.y + bb.y);
      o4[2] = f2bf((a[k].z - m) * rs * gg.z + bb.z);
      o4[3] = f2bf((a[k].w - m) * rs * gg.w + bb.w);
      nst[j4] = o4;
      lst[j4] = o4;
    }
  }
  __syncthreads();
  // MFMA: M=16 heads (A=wkqT), N=16 s-rows (B=LDS rows), K=2048 over 8 waves
  const int m16 = l & 15, kg = l >> 4;
  f32x4 c = {0.f, 0.f, 0.f, 0.f};
  const unsigned short* aptr = wkqT + (size_t)m16 * D + w * 256 + kg * 8;
  const unsigned short* bptr = rows + m16 * RSTRIDE + w * 256 + kg * 8;
  #pragma unroll
  for(int kk = 0; kk < 8; kk++){
    bf16x8 av = *(const bf16x8*)(aptr + kk * 32);
    bf16x8 bv = *(const bf16x8*)(bptr + kk * 32);
    c = __builtin_amdgcn_mfma_f32_16x16x32_bf16(av, bv, c, 0, 0, 0);
  }
  cred[w][l] = c;
  __syncthreads();
  if(w == 0){
    f32x4 cs_ = cred[0][l];
    #pragma unroll
    for(int p = 1; p < 8; p++){
      f32x4 cp = cred[p][l];
      cs_[0] += cp[0]; cs_[1] += cp[1]; cs_[2] += cp[2]; cs_[3] += cp[3];
    }
    // C layout: col(=s-row) = l&15, row(=head) = kg*4 + reg
    float sc[4], mr[4], rr[4];
    #pragma unroll
    for(int rg = 0; rg < 4; rg++) sc[rg] = (cs_[rg] + qb[kg * 4 + rg]) * SCALE;
    float4 st4;
    st4.x = sc[0]; st4.y = sc[1]; st4.z = sc[2]; st4.w = sc[3];
    *(float4*)(scores + (size_t)(s0 + m16) * H + kg * 4) = st4;
    #pragma unroll
    for(int rg = 0; rg < 4; rg++){
      float mx = sc[rg];
      #pragma unroll
      for(int o = 1; o < 16; o <<= 1) mx = fmaxf(mx, __shfl_xor(mx, o));
      mr[rg] = mx;
    }
    #pragma unroll
    for(int rg = 0; rg < 4; rg++){
      float e = __expf(sc[rg] - mr[rg]);
      #pragma unroll
      for(int o = 1; o < 16; o <<= 1) e += __shfl_xor(e, o);
      rr[rg] = e;
    }
    if(m16 == 0){
      float4 bm4, bs4;
      bm4.x = mr[0]; bm4.y = mr[1]; bm4.z = mr[2]; bm4.w = mr[3];
      bs4.x = rr[0]; bs4.y = rr[1]; bs4.z = rr[2]; bs4.w = rr[3];
      *(float4*)(bm + (size_t)blockIdx.x * H + kg * 4) = bm4;
      *(float4*)(bs + (size_t)blockIdx.x * H + kg * 4) = bs4;
    }
  }
}

// ---------------- K4: actx partials, inline softmax-final stats + exp ----------------
// grid (8 jc, 64 sc of 128 rows)
__global__ __launch_bounds__(256) void k_actx(const unsigned short* __restrict__ nall,
    const float* __restrict__ scores, const float* __restrict__ bm,
    const float* __restrict__ bs, float* __restrict__ part){
  __shared__ float pl[16 * 128]; // [h][ss]
  __shared__ float mh_s[16], ih_s[16];
  const int jc = blockIdx.x, sc = blockIdx.y, t = threadIdx.x;
  {
    const int hh = t >> 4, u = t & 15;
    float m = -3.0e38f;
    for(int i = 0; i < 32; i++) m = fmaxf(m, bm[(size_t)(u + 16 * i) * H + hh]);
    #pragma unroll
    for(int o = 1; o < 16; o <<= 1) m = fmaxf(m, __shfl_xor(m, o));
    float ssum = 0.f;
    for(int i = 0; i < 32; i++){
      size_t idx = (size_t)(u + 16 * i) * H + hh;
      ssum += bs[idx] * __expf(bm[idx] - m);
    }
    #pragma unroll
    for(int o = 1; o < 16; o <<= 1) ssum += __shfl_xor(ssum, o);
    if(u == 0){ mh_s[hh] = m; ih_s[hh] = 1.f / ssum; }
  }
  __syncthreads();
  const int s0 = sc * 128;
  #pragma unroll
  for(int u = 0; u < 8; u++){
    int idx = t + 256 * u;
    int ss = idx >> 4, hh = idx & 15;
    pl[hh * 128 + ss] = __expf(scores[(size_t)(s0 + ss) * H + hh] - mh_s[hh]) * ih_s[hh];
  }
  __syncthreads();
  const int j = jc * 256 + t;
  float acc[16];
  #pragma unroll
  for(int h = 0; h < 16; h++) acc[h] = 0.f;
  for(int s8 = 0; s8 < 16; s8++){
    float n[8];
    #pragma unroll
    for(int e = 0; e < 8; e++) n[e] = bf2f(nall[(size_t)(s0 + s8 * 8 + e) * D + j]);
    #pragma unroll
    for(int h = 0; h < 16; h++){
      float4 pa = ((const float4*)pl)[h * 32 + s8 * 2];
      float4 pb = ((const float4*)pl)[h * 32 + s8 * 2 + 1];
      acc[h] = fmaf(pa.x, n[0], fmaf(pa.y, n[1], fmaf(pa.z, n[2], fmaf(pa.w, n[3], acc[h]))));
      acc[h] = fmaf(pb.x, n[4], fmaf(pb.y, n[5], fmaf(pb.z, n[6], fmaf(pb.w, n[7], acc[h]))));
    }
  }
  #pragma unroll
  for(int h = 0; h < 16; h++) part[((size_t)sc * 16 + h) * D + j] = acc[h];
}

// ---------------- K5: reduce actx + wv GEMV ----------------
// grid (16 h, 32 jc of 64 j)
__global__ __launch_bounds__(256) void k_wv(const float* __restrict__ part,
    const float* __restrict__ wv, float* __restrict__ part_wv){
  __shared__ float a4[4][64];
  __shared__ float as[64];
  __shared__ float red2[2][128];
  const int h = blockIdx.x, jc = blockIdx.y, t = threadIdx.x;
  const int j0 = jc * 64;
  const int jq = t & 63, qq = t >> 6;
  float s_ = 0.f;
  #pragma unroll
  for(int u = 0; u < 16; u++){
    int sc = qq * 16 + u;
    s_ += part[((size_t)sc * 16 + h) * D + j0 + jq];
  }
  a4[qq][jq] = s_;
  __syncthreads();
  if(t < 64) as[t] = a4[0][t] + a4[1][t] + a4[2][t] + a4[3][t];
  __syncthreads();
  const int hf = t >> 7, il = t & 127;
  const int i = h * DH + il;
  float acc = 0.f;
  #pragma unroll
  for(int u = 0; u < 32; u++){
    int jj = hf * 32 + u;
    acc = fmaf(as[jj], wv[(size_t)(j0 + jj) * D + i], acc);
  }
  red2[hf][il] = acc;
  __syncthreads();
  if(t < 128) part_wv[(size_t)jc * D + h * DH + t] = red2[0][t] + red2[1][t];
}

// ---------------- K6: reduce wv partials (+bv) + wo GEMV ----------------
// grid (8 ic, 16 jc of 128 j)
__global__ __launch_bounds__(256) void k_wo(const float* __restrict__ part_wv,
    const float* __restrict__ bv, const float* __restrict__ wo,
    float* __restrict__ part_wo){
  __shared__ float oa[128];
  const int ic = blockIdx.x, jc = blockIdx.y, t = threadIdx.x;
  const int j0 = jc * 128;
  if(t < 128){
    float s = bv[j0 + t];
    #pragma unroll
    for(int p = 0; p < 32; p++) s += part_wv[(size_t)p * D + j0 + t];
    oa[t] = s;
  }
  __syncthreads();
  const int i = ic * 256 + t;
  float acc = 0.f;
  #pragma unroll 8
  for(int jj = 0; jj < 128; jj++)
    acc = fmaf(oa[jj], wo[(size_t)(j0 + jj) * D + i], acc);
  part_wo[(size_t)jc * D + i] = acc;
}

// ---------------- K7: f1 partials with inline x + LN2 ----------------
// grid (32 oc, 16 jc of 128 j); x recomputed from L2-hot part_wo
__global__ __launch_bounds__(256) void k_f1(const float* __restrict__ self_tok,
    const float* __restrict__ bo, const float* __restrict__ part_wo,
    const float* __restrict__ g2, const float* __restrict__ b2,
    const float* __restrict__ w1, float* __restrict__ part_f1){
  __shared__ float buf[8];
  __shared__ float xs[128];
  const int oc = blockIdx.x, jc = blockIdx.y, t = threadIdx.x;
  float sum = 0.f, sq = 0.f;
  #pragma unroll
  for(int u = 0; u < 8; u++){
    int i = t + 256 * u;
    float s = self_tok[i] + bo[i];
    #pragma unroll
    for(int p = 0; p < 16; p++) s += part_wo[(size_t)p * D + i];
    sum += s; sq += s * s;
  }
  block_sum2<4>(sum, sq, buf);
  const float m2 = sum * (1.f / D);
  const float r2 = rsqrtf(sq * (1.f / D) - m2 * m2 + EPS);
  if(t < 128){
    int j = jc * 128 + t;
    float s = self_tok[j] + bo[j];
    #pragma unroll
    for(int p = 0; p < 16; p++) s += part_wo[(size_t)p * D + j];
    xs[t] = (s - m2) * r2 * g2[j] + b2[j];
  }
  __syncthreads();
  const int o = oc * 256 + t;
  float acc = 0.f;
  #pragma unroll 8
  for(int jj = 0; jj < 128; jj++)
    acc = fmaf(xs[jj], w1[(size_t)(jc * 128 + jj) * (4 * D) + o], acc);
  part_f1[(size_t)jc * (4 * D) + o] = acc;
}

// ---------------- K8: f2 partials with inline f1-reduce + gelu ----------------
// grid (8 ic, 64 jc of 128 hidden)
__global__ __launch_bounds__(256) void k_f2(const float* __restrict__ part_f1,
    const float* __restrict__ b_f1, const float* __restrict__ w2,
    float* __restrict__ part_f2){
  __shared__ float hs[128];
  const int ic = blockIdx.x, jc = blockIdx.y, t = threadIdx.x;
  if(t < 128){
    int jh = jc * 128 + t;
    float s = b_f1[jh];
    #pragma unroll
    for(int p = 0; p < 16; p++) s += part_f1[(size_t)p * (4 * D) + jh];
    hs[t] = gelu(s);
  }
  __syncthreads();
  const int i = ic * 256 + t;
  float acc = 0.f;
  #pragma unroll 8
  for(int jj = 0; jj < 128; jj++)
    acc = fmaf(hs[jj], w2[(size_t)(jc * 128 + jj) * D + i], acc);
  part_f2[(size_t)jc * D + i] = acc;
}

// ---------------- K9: out = x + b_f2 + sum(part_f2), x recomputed ----------------
__global__ __launch_bounds__(256) void k_final(const float* __restrict__ part_f2,
    const float* __restrict__ part_wo, const float* __restrict__ self_tok,
    const float* __restrict__ bo, const float* __restrict__ b_f2,
    float* __restrict__ out){
  const int i = blockIdx.x * 256 + threadIdx.x;
  float s = self_tok[i] + bo[i];
  #pragma unroll
  for(int p = 0; p < 16; p++) s += part_wo[(size_t)p * D + i];
  s += b_f2[i];
  #pragma unroll 8
  for(int jc = 0; jc < 64; jc++) s += part_f2[(size_t)jc * D + i];
  out[i] = s;
}

extern "C" void kernel_launch(void* const* d_in, const int* in_sizes, int n_in,
                              void* d_out, int out_size, void* d_ws, size_t ws_size,
                              hipStream_t stream){
  const float* self_tok = (const float*)d_in[0];
  const float* all_toks = (const float*)d_in[1];
  const float* wq = (const float*)d_in[2];
  const float* bq = (const float*)d_in[3];
  const float* wk = (const float*)d_in[4];
  const float* bk = (const float*)d_in[5];
  const float* wv = (const float*)d_in[6];
  const float* bv = (const float*)d_in[7];
  const float* wo = (const float*)d_in[8];
  const float* bo = (const float*)d_in[9];
  const float* g1 = (const float*)d_in[10];
  const float* b1 = (const float*)d_in[11];
  const float* g2 = (const float*)d_in[12];
  const float* b2 = (const float*)d_in[13];
  const float* w1 = (const float*)d_in[14];
  const float* b_f1 = (const float*)d_in[15];
  const float* w2 = (const float*)d_in[16];
  const float* b_f2 = (const float*)d_in[17];
  float* out = (float*)d_out;

  char* wptr = (char*)d_ws;
  auto alloc = [&](size_t bytes) -> void* {
    void* p = (void*)wptr;
    wptr += (bytes + 255) & ~(size_t)255;
    return p;
  };
  unsigned short* n_all = (unsigned short*)alloc((size_t)S * D * 2);
  unsigned short* wkqT  = (unsigned short*)alloc((size_t)H * D * 2);
  float* scores    = (float*)alloc((size_t)S * H * 4);
  float* bm        = (float*)alloc((size_t)(S / 16) * H * 4);
  float* bs        = (float*)alloc((size_t)(S / 16) * H * 4);
  float* q         = (float*)alloc((size_t)D * 4);
  float* qb        = (float*)alloc(64);
  float* part_actx = (float*)alloc((size_t)64 * H * D * 4);
  float* part_wv   = (float*)alloc((size_t)32 * D * 4);
  float* part_wo   = (float*)alloc((size_t)16 * D * 4);
  float* part_f1   = (float*)alloc((size_t)16 * 4 * D * 4);
  float* part_f2   = (float*)alloc((size_t)64 * D * 4);

  k_q<<<64, 512, 0, stream>>>(self_tok, g1, b1, wq, bq, q);
  k_wkq<<<D + 1, 256, 0, stream>>>(wk, bk, q, wkqT, qb);
  k_ln_sc<<<S / 16, 512, 0, stream>>>(all_toks, g1, b1, wkqT, qb, n_all, scores, bm, bs);
  k_actx<<<dim3(8, 64), 256, 0, stream>>>(n_all, scores, bm, bs, part_actx);
  k_wv<<<dim3(16, 32), 256, 0, stream>>>(part_actx, wv, part_wv);
  k_wo<<<dim3(8, 16), 256, 0, stream>>>(part_wv, bv, wo, part_wo);
  k_f1<<<dim3(32, 16), 256, 0, stream>>>(self_tok, bo, part_wo, g2, b2, w1, part_f1);
  k_f2<<<dim3(8, 64), 256, 0, stream>>>(part_f1, b_f1, w2, part_f2);
  k_final<<<8, 256, 0, stream>>>(part_f2, part_wo, self_tok, bo, b_f2, out);
}

// Round 7
// 138.674 us; speedup vs baseline: 1.2221x; 1.2221x over previous
//
#include <hip/hip_runtime.h>

#define DEV __device__ __forceinline__

constexpr int D  = 2048;
constexpr int H  = 16;
constexpr int DH = 128;
constexpr int S  = 8192;
constexpr float EPS = 1e-6f;
constexpr float SCALE = 0.08838834764831845f; // DH^-0.5

typedef unsigned short ushortv4 __attribute__((ext_vector_type(4)));
typedef short bf16x8 __attribute__((ext_vector_type(8)));
typedef float f32x4 __attribute__((ext_vector_type(4)));

DEV float bf2f(unsigned short u){ return __uint_as_float(((unsigned int)u) << 16); }
DEV unsigned short f2bf(float f){
  unsigned int x = __float_as_uint(f);
  unsigned int r = x + 0x7fffu + ((x >> 16) & 1u);
  return (unsigned short)(r >> 16);
}

DEV float gelu(float x){
  float x3 = x * x * x;
  return 0.5f * x * (1.f + tanhf(0.7978845608028654f * (x + 0.044715f * x3)));
}

// block-wide sum of two values; block = NW*64 threads
template<int NW>
DEV void block_sum2(float& a, float& b, float* buf){
  #pragma unroll
  for(int o = 32; o; o >>= 1){ a += __shfl_xor(a, o); b += __shfl_xor(b, o); }
  const int w = threadIdx.x >> 6;
  if((threadIdx.x & 63) == 0){ buf[w] = a; buf[NW + w] = b; }
  __syncthreads();
  a = buf[0]; b = buf[NW];
  #pragma unroll
  for(int i = 1; i < NW; i++){ a += buf[i]; b += buf[NW + i]; }
}

// ---------------- K1: LayerNorm all_toks -> n_all (bf16) ----------------
__global__ __launch_bounds__(256) void k_ln_all(const float* __restrict__ at,
    const float* __restrict__ g1, const float* __restrict__ b1,
    unsigned short* __restrict__ nall){
  __shared__ float buf[8];
  const int t = threadIdx.x;
  const size_t s = blockIdx.x;
  const float4* row = (const float4*)(at + s * D);
  float4 a = row[t], c = row[t + 256];
  float sum = a.x + a.y + a.z + a.w + c.x + c.y + c.z + c.w;
  float sq  = a.x*a.x + a.y*a.y + a.z*a.z + a.w*a.w
            + c.x*c.x + c.y*c.y + c.z*c.z + c.w*c.w;
  block_sum2<4>(sum, sq, buf);
  const float m = sum * (1.f / D);
  const float r = rsqrtf(sq * (1.f / D) - m * m + EPS);
  const float4* g4 = (const float4*)g1;
  const float4* b4 = (const float4*)b1;
  float4 ga = g4[t], gc = g4[t + 256], ba = b4[t], bc = b4[t + 256];
  ushortv4 oa, oc;
  oa[0] = f2bf((a.x - m) * r * ga.x + ba.x);
  oa[1] = f2bf((a.y - m) * r * ga.y + ba.y);
  oa[2] = f2bf((a.z - m) * r * ga.z + ba.z);
  oa[3] = f2bf((a.w - m) * r * ga.w + ba.w);
  oc[0] = f2bf((c.x - m) * r * gc.x + bc.x);
  oc[1] = f2bf((c.y - m) * r * gc.y + bc.y);
  oc[2] = f2bf((c.z - m) * r * gc.z + bc.z);
  oc[3] = f2bf((c.w - m) * r * gc.w + bc.w);
  ushortv4* dst = (ushortv4*)(nall + s * D);
  dst[t] = oa;
  dst[t + 256] = oc;
}

// ---------------- K2: q = LN(self_tok) @ wq + bq (64 blocks x 512) ----------------
__global__ __launch_bounds__(512) void k_q(const float* __restrict__ st,
    const float* __restrict__ g1, const float* __restrict__ b1,
    const float* __restrict__ wq, const float* __restrict__ bq,
    float* __restrict__ q){
  __shared__ float buf[16];
  __shared__ float ns[D];
  __shared__ float red[16][32];
  const int t = threadIdx.x;
  float4 a = ((const float4*)st)[t];
  float sum = a.x + a.y + a.z + a.w;
  float sq  = a.x*a.x + a.y*a.y + a.z*a.z + a.w*a.w;
  block_sum2<8>(sum, sq, buf);
  const float m = sum * (1.f / D);
  const float r = rsqrtf(sq * (1.f / D) - m * m + EPS);
  float4 g = ((const float4*)g1)[t], b = ((const float4*)b1)[t];
  float4 na;
  na.x = (a.x - m) * r * g.x + b.x;
  na.y = (a.y - m) * r * g.y + b.y;
  na.z = (a.z - m) * r * g.z + b.z;
  na.w = (a.w - m) * r * g.w + b.w;
  ((float4*)ns)[t] = na;
  __syncthreads();
  const int i = blockIdx.x * 32 + (t & 31);
  const int sl = t >> 5;   // 0..15
  float acc = 0.f;
  #pragma unroll 8
  for(int jj = 0; jj < 128; jj++){
    int j = sl * 128 + jj;
    acc = fmaf(ns[j], wq[(size_t)j * D + i], acc);
  }
  red[sl][t & 31] = acc;
  __syncthreads();
  if(t < 32){
    float s = bq[blockIdx.x * 32 + t];
    #pragma unroll
    for(int p = 0; p < 16; p++) s += red[p][t];
    q[blockIdx.x * 32 + t] = s;
  }
}

// ---------------- K3: wkqT[h][j] (bf16) = wk[j, h*128:+128].q ; qb[h] = bk.q ----------------
__global__ __launch_bounds__(256) void k_wkq(const float* __restrict__ wk,
    const float* __restrict__ bk, const float* __restrict__ q,
    unsigned short* __restrict__ wkqT, float* __restrict__ qb){
  const int j = blockIdx.x, t = threadIdx.x;
  const float* src = (j < D) ? (wk + (size_t)j * D) : bk;
  const float4* s4 = (const float4*)src;
  const float4* q4 = (const float4*)q;
  float4 a = s4[2 * t], c = s4[2 * t + 1], qa = q4[2 * t], qc = q4[2 * t + 1];
  float p = a.x*qa.x + a.y*qa.y + a.z*qa.z + a.w*qa.w
          + c.x*qc.x + c.y*qc.y + c.z*qc.z + c.w*qc.w;
  #pragma unroll
  for(int o = 1; o < 16; o <<= 1) p += __shfl_xor(p, o);
  if((t & 15) == 0){
    const int h = t >> 4;
    if(j < D) wkqT[(size_t)h * D + j] = f2bf(p);
    else      qb[h] = p;
  }
}

// ---------------- K4: scores via MFMA ----------------
// block = 4 waves, 16 s-rows, each wave K=512 (16 mfma), LDS-reduce C.
__global__ __launch_bounds__(256) void k_scores(
    const unsigned short* __restrict__ nall,  // [S][D] bf16
    const unsigned short* __restrict__ wkqT,  // [H][D] bf16
    const float* __restrict__ qb,
    float* __restrict__ scores,               // [S][H]
    float* __restrict__ bm, float* __restrict__ bs){ // [S/16][H]
  __shared__ f32x4 cred[4][64];
  const int t = threadIdx.x;
  const int w = t >> 6, lane = t & 63;
  const int s0 = blockIdx.x * 16;
  const int m16 = lane & 15;       // A row (head) and B col (s-row)
  const int kg  = lane >> 4;       // k-group (0..3)
  f32x4 c = {0.f, 0.f, 0.f, 0.f};
  const int kbase = w * 512 + kg * 8;
  const unsigned short* aptr = wkqT + (size_t)m16 * D + kbase;
  const unsigned short* bptr = nall + (size_t)(s0 + m16) * D + kbase;
  #pragma unroll
  for(int kk = 0; kk < 16; kk++){
    bf16x8 av = *(const bf16x8*)(aptr + kk * 32);
    bf16x8 bv = *(const bf16x8*)(bptr + kk * 32);
    c = __builtin_amdgcn_mfma_f32_16x16x32_bf16(av, bv, c, 0, 0, 0);
  }
  cred[w][lane] = c;
  __syncthreads();
  if(w == 0){
    f32x4 c0 = cred[0][lane], c1 = cred[1][lane], c2 = cred[2][lane], c3 = cred[3][lane];
    float sc[4], mr[4], rr[4];
    #pragma unroll
    for(int rg = 0; rg < 4; rg++){
      float v = c0[rg] + c1[rg] + c2[rg] + c3[rg];
      sc[rg] = (v + qb[kg * 4 + rg]) * SCALE;
    }
    float4 st4;
    st4.x = sc[0]; st4.y = sc[1]; st4.z = sc[2]; st4.w = sc[3];
    *(float4*)(scores + (size_t)(s0 + m16) * H + kg * 4) = st4;
    #pragma unroll
    for(int rg = 0; rg < 4; rg++){
      float mx = sc[rg];
      #pragma unroll
      for(int o = 1; o < 16; o <<= 1) mx = fmaxf(mx, __shfl_xor(mx, o));
      mr[rg] = mx;
    }
    #pragma unroll
    for(int rg = 0; rg < 4; rg++){
      float e = __expf(sc[rg] - mr[rg]);
      #pragma unroll
      for(int o = 1; o < 16; o <<= 1) e += __shfl_xor(e, o);
      rr[rg] = e;
    }
    if(m16 == 0){
      float4 bm4, bs4;
      bm4.x = mr[0]; bm4.y = mr[1]; bm4.z = mr[2]; bm4.w = mr[3];
      bs4.x = rr[0]; bs4.y = rr[1]; bs4.z = rr[2]; bs4.w = rr[3];
      *(float4*)(bm + (size_t)blockIdx.x * H + kg * 4) = bm4;
      *(float4*)(bs + (size_t)blockIdx.x * H + kg * 4) = bs4;
    }
  }
}

// ---------------- K5: final softmax stats per head ----------------
__global__ __launch_bounds__(256) void k_smfinal(const float* __restrict__ bm,
    const float* __restrict__ bs, float* __restrict__ mh, float* __restrict__ ih){
  __shared__ float red[4];
  const int h = blockIdx.x, t = threadIdx.x;
  float m = -3.0e38f;
  for(int c = t; c < 512; c += 256) m = fmaxf(m, bm[(size_t)c * H + h]);
  #pragma unroll
  for(int o = 32; o; o >>= 1) m = fmaxf(m, __shfl_xor(m, o));
  if((t & 63) == 0) red[t >> 6] = m;
  __syncthreads();
  m = fmaxf(fmaxf(red[0], red[1]), fmaxf(red[2], red[3]));
  __syncthreads();
  float s = 0.f;
  for(int c = t; c < 512; c += 256) s += bs[(size_t)c * H + h] * __expf(bm[(size_t)c * H + h] - m);
  #pragma unroll
  for(int o = 32; o; o >>= 1) s += __shfl_xor(s, o);
  if((t & 63) == 0) red[t >> 6] = s;
  __syncthreads();
  if(t == 0){
    mh[h] = m;
    ih[h] = 1.f / (red[0] + red[1] + red[2] + red[3]);
  }
}

// ---------------- K6: actx partials, vectorized ----------------
// grid (4 jc, 64 sc of 128 rows), 256 threads; thread owns j = jc*512 + 2t, +1.
// plT[ss][h] staged (coalesced fill, broadcast b128 reads); acc[16][2] = 32 VGPR.
__global__ __launch_bounds__(256) void k_actx(const unsigned short* __restrict__ nall,
    const float* __restrict__ scores, const float* __restrict__ mh,
    const float* __restrict__ ih, float* __restrict__ part){
  __shared__ float plT[128][16]; // [ss][h] : 8 KB
  __shared__ float mh_s[16], ih_s[16];
  const int jc = blockIdx.x, sc = blockIdx.y, t = threadIdx.x;
  if(t < 16){ mh_s[t] = mh[t]; ih_s[t] = ih[t]; }
  __syncthreads();
  const int s0 = sc * 128;
  #pragma unroll
  for(int u = 0; u < 8; u++){
    int idx = t + 256 * u;
    int ss = idx >> 4, hh = idx & 15;
    plT[ss][hh] = __expf(scores[(size_t)(s0 + ss) * H + hh] - mh_s[hh]) * ih_s[hh];
  }
  __syncthreads();
  const int j = jc * 512 + 2 * t;
  float acc[16][2];
  #pragma unroll
  for(int h = 0; h < 16; h++){ acc[h][0] = 0.f; acc[h][1] = 0.f; }
  #pragma unroll 2
  for(int ss = 0; ss < 128; ss++){
    unsigned int nv = *(const unsigned int*)(nall + (size_t)(s0 + ss) * D + j);
    float n0 = bf2f((unsigned short)(nv & 0xffffu));
    float n1 = bf2f((unsigned short)(nv >> 16));
    const float4* pp = (const float4*)plT[ss];
    #pragma unroll
    for(int hq = 0; hq < 4; hq++){
      float4 p4 = pp[hq];
      acc[hq*4+0][0] = fmaf(p4.x, n0, acc[hq*4+0][0]);
      acc[hq*4+0][1] = fmaf(p4.x, n1, acc[hq*4+0][1]);
      acc[hq*4+1][0] = fmaf(p4.y, n0, acc[hq*4+1][0]);
      acc[hq*4+1][1] = fmaf(p4.y, n1, acc[hq*4+1][1]);
      acc[hq*4+2][0] = fmaf(p4.z, n0, acc[hq*4+2][0]);
      acc[hq*4+2][1] = fmaf(p4.z, n1, acc[hq*4+2][1]);
      acc[hq*4+3][0] = fmaf(p4.w, n0, acc[hq*4+3][0]);
      acc[hq*4+3][1] = fmaf(p4.w, n1, acc[hq*4+3][1]);
    }
  }
  #pragma unroll
  for(int h = 0; h < 16; h++){
    float2 st2; st2.x = acc[h][0]; st2.y = acc[h][1];
    *(float2*)(part + ((size_t)sc * 16 + h) * D + j) = st2;
  }
}

// ---------------- K7: reduce actx + wv GEMV ----------------
// grid (16 h, 32 jc of 64 j)
__global__ __launch_bounds__(256) void k_wv(const float* __restrict__ part,
    const float* __restrict__ wv, float* __restrict__ part_wv){
  __shared__ float a4[4][64];
  __shared__ float as[64];
  __shared__ float red2[2][128];
  const int h = blockIdx.x, jc = blockIdx.y, t = threadIdx.x;
  const int j0 = jc * 64;
  const int jq = t & 63, qq = t >> 6;
  float s_ = 0.f;
  #pragma unroll
  for(int u = 0; u < 16; u++){
    int sc = qq * 16 + u;
    s_ += part[((size_t)sc * 16 + h) * D + j0 + jq];
  }
  a4[qq][jq] = s_;
  __syncthreads();
  if(t < 64) as[t] = a4[0][t] + a4[1][t] + a4[2][t] + a4[3][t];
  __syncthreads();
  const int hf = t >> 7, il = t & 127;
  const int i = h * DH + il;
  float acc = 0.f;
  #pragma unroll
  for(int u = 0; u < 32; u++){
    int jj = hf * 32 + u;
    acc = fmaf(as[jj], wv[(size_t)(j0 + jj) * D + i], acc);
  }
  red2[hf][il] = acc;
  __syncthreads();
  if(t < 128) part_wv[(size_t)jc * D + h * DH + t] = red2[0][t] + red2[1][t];
}

// ---------------- K8: reduce wv partials (+bv) + wo GEMV ----------------
// grid (8 ic, 16 jc of 128 j)
__global__ __launch_bounds__(256) void k_wo(const float* __restrict__ part_wv,
    const float* __restrict__ bv, const float* __restrict__ wo,
    float* __restrict__ part_wo){
  __shared__ float oa[128];
  const int ic = blockIdx.x, jc = blockIdx.y, t = threadIdx.x;
  const int j0 = jc * 128;
  if(t < 128){
    float s = bv[j0 + t];
    #pragma unroll
    for(int p = 0; p < 32; p++) s += part_wv[(size_t)p * D + j0 + t];
    oa[t] = s;
  }
  __syncthreads();
  const int i = ic * 256 + t;
  float acc = 0.f;
  #pragma unroll 8
  for(int jj = 0; jj < 128; jj++)
    acc = fmaf(oa[jj], wo[(size_t)(j0 + jj) * D + i], acc);
  part_wo[(size_t)jc * D + i] = acc;
}

// ---------------- K9: x = self + bo + sum(part_wo); per-block LN2 stats ----------------
__global__ __launch_bounds__(256) void k_x(const float* __restrict__ self_tok,
    const float* __restrict__ bo, const float* __restrict__ part_wo,
    float* __restrict__ x, float* __restrict__ xstat){
  __shared__ float buf[8];
  const int b = blockIdx.x, t = threadIdx.x;
  const int i = b * 256 + t;
  float s = self_tok[i] + bo[i];
  #pragma unroll
  for(int p = 0; p < 16; p++) s += part_wo[(size_t)p * D + i];
  x[i] = s;
  float sq = s * s;
  block_sum2<4>(s, sq, buf);
  if(t == 0){ xstat[2 * b] = s; xstat[2 * b + 1] = sq; }
}

// ---------------- K10: f1 partials with inline LN2 ----------------
// grid (32 oc, 16 jc of 128 j)
__global__ __launch_bounds__(256) void k_f1(const float* __restrict__ x,
    const float* __restrict__ xstat, const float* __restrict__ g2,
    const float* __restrict__ b2, const float* __restrict__ w1,
    float* __restrict__ part_f1){
  __shared__ float xs[128];
  __shared__ float stat[2];
  const int oc = blockIdx.x, jc = blockIdx.y, t = threadIdx.x;
  if(t == 0){
    float s1 = 0.f, s2 = 0.f;
    #pragma unroll
    for(int p = 0; p < 8; p++){ s1 += xstat[2 * p]; s2 += xstat[2 * p + 1]; }
    float m = s1 * (1.f / D);
    stat[0] = m;
    stat[1] = rsqrtf(s2 * (1.f / D) - m * m + EPS);
  }
  __syncthreads();
  if(t < 128){
    int j = jc * 128 + t;
    xs[t] = (x[j] - stat[0]) * stat[1] * g2[j] + b2[j];
  }
  __syncthreads();
  const int o = oc * 256 + t;
  float acc = 0.f;
  #pragma unroll 8
  for(int jj = 0; jj < 128; jj++)
    acc = fmaf(xs[jj], w1[(size_t)(jc * 128 + jj) * (4 * D) + o], acc);
  part_f1[(size_t)jc * (4 * D) + o] = acc;
}

// ---------------- K11: f2 partials with inline f1-reduce + gelu ----------------
// grid (8 ic, 64 jc of 128 hidden)
__global__ __launch_bounds__(256) void k_f2(const float* __restrict__ part_f1,
    const float* __restrict__ b_f1, const float* __restrict__ w2,
    float* __restrict__ part_f2){
  __shared__ float hs[128];
  const int ic = blockIdx.x, jc = blockIdx.y, t = threadIdx.x;
  if(t < 128){
    int jh = jc * 128 + t;
    float s = b_f1[jh];
    #pragma unroll
    for(int p = 0; p < 16; p++) s += part_f1[(size_t)p * (4 * D) + jh];
    hs[t] = gelu(s);
  }
  __syncthreads();
  const int i = ic * 256 + t;
  float acc = 0.f;
  #pragma unroll 8
  for(int jj = 0; jj < 128; jj++)
    acc = fmaf(hs[jj], w2[(size_t)(jc * 128 + jj) * D + i], acc);
  part_f2[(size_t)jc * D + i] = acc;
}

// ---------------- K12: out = x + b_f2 + sum(part_f2) ----------------
__global__ __launch_bounds__(256) void k_final(const float* __restrict__ part_f2,
    const float* __restrict__ x, const float* __restrict__ b_f2,
    float* __restrict__ out){
  const int i = blockIdx.x * 256 + threadIdx.x;
  float s = x[i] + b_f2[i];
  #pragma unroll 8
  for(int jc = 0; jc < 64; jc++) s += part_f2[(size_t)jc * D + i];
  out[i] = s;
}

extern "C" void kernel_launch(void* const* d_in, const int* in_sizes, int n_in,
                              void* d_out, int out_size, void* d_ws, size_t ws_size,
                              hipStream_t stream){
  const float* self_tok = (const float*)d_in[0];
  const float* all_toks = (const float*)d_in[1];
  const float* wq = (const float*)d_in[2];
  const float* bq = (const float*)d_in[3];
  const float* wk = (const float*)d_in[4];
  const float* bk = (const float*)d_in[5];
  const float* wv = (const float*)d_in[6];
  const float* bv = (const float*)d_in[7];
  const float* wo = (const float*)d_in[8];
  const float* bo = (const float*)d_in[9];
  const float* g1 = (const float*)d_in[10];
  const float* b1 = (const float*)d_in[11];
  const float* g2 = (const float*)d_in[12];
  const float* b2 = (const float*)d_in[13];
  const float* w1 = (const float*)d_in[14];
  const float* b_f1 = (const float*)d_in[15];
  const float* w2 = (const float*)d_in[16];
  const float* b_f2 = (const float*)d_in[17];
  float* out = (float*)d_out;

  char* wptr = (char*)d_ws;
  auto alloc = [&](size_t bytes) -> void* {
    void* p = (void*)wptr;
    wptr += (bytes + 255) & ~(size_t)255;
    return p;
  };
  unsigned short* n_all = (unsigned short*)alloc((size_t)S * D * 2);
  unsigned short* wkqT  = (unsigned short*)alloc((size_t)H * D * 2);
  float* scores    = (float*)alloc((size_t)S * H * 4);
  float* bm        = (float*)alloc((size_t)(S / 16) * H * 4);
  float* bs        = (float*)alloc((size_t)(S / 16) * H * 4);
  float* mh        = (float*)alloc(64);
  float* ih        = (float*)alloc(64);
  float* q         = (float*)alloc((size_t)D * 4);
  float* qb        = (float*)alloc(64);
  float* part_actx = (float*)alloc((size_t)64 * H * D * 4);
  float* part_wv   = (float*)alloc((size_t)32 * D * 4);
  float* part_wo   = (float*)alloc((size_t)16 * D * 4);
  float* xbuf      = (float*)alloc((size_t)D * 4);
  float* xstat     = (float*)alloc(64);
  float* part_f1   = (float*)alloc((size_t)16 * 4 * D * 4);
  float* part_f2   = (float*)alloc((size_t)64 * D * 4);

  k_q<<<64, 512, 0, stream>>>(self_tok, g1, b1, wq, bq, q);
  k_wkq<<<D + 1, 256, 0, stream>>>(wk, bk, q, wkqT, qb);
  k_ln_all<<<S, 256, 0, stream>>>(all_toks, g1, b1, n_all);
  k_scores<<<S / 16, 256, 0, stream>>>(n_all, wkqT, qb, scores, bm, bs);
  k_smfinal<<<H, 256, 0, stream>>>(bm, bs, mh, ih);
  k_actx<<<dim3(4, 64), 256, 0, stream>>>(n_all, scores, mh, ih, part_actx);
  k_wv<<<dim3(16, 32), 256, 0, stream>>>(part_actx, wv, part_wv);
  k_wo<<<dim3(8, 16), 256, 0, stream>>>(part_wv, bv, wo, part_wo);
  k_x<<<8, 256, 0, stream>>>(self_tok, bo, part_wo, xbuf, xstat);
  k_f1<<<dim3(32, 16), 256, 0, stream>>>(xbuf, xstat, g2, b2, w1, part_f1);
  k_f2<<<dim3(8, 64), 256, 0, stream>>>(part_f1, b_f1, w2, part_f2);
  k_final<<<8, 256, 0, stream>>>(part_f2, xbuf, b_f2, out);
}